// Round 1
// baseline (1189.086 us; speedup 1.0000x reference)
//
#include <hip/hip_runtime.h>
#include <hip/hip_bf16.h>
#include <cstdint>
#include <cstddef>

// Problem: B=2048, C=8, D=2048. All per-channel GEMMs are 2048x2048x2048.
#define NN 2048
#define CCH 8

using f32x4  = __attribute__((ext_vector_type(4))) float;
using bf16x8 = __attribute__((ext_vector_type(8))) __bf16;

__device__ __forceinline__ unsigned short f2bf(float f) {
  union { __bf16 b; unsigned short u; } v; v.b = (__bf16)f; return v.u;
}

// async global->LDS, 16B per lane. LDS dest is wave-uniform base; HW scatters lane l to base + l*16.
__device__ __forceinline__ void async_load16(const void* gp, void* lp) {
  __builtin_amdgcn_global_load_lds(
      (__attribute__((address_space(1))) void*)(void*)gp,
      (__attribute__((address_space(3))) void*)lp, 16, 0, 0);
}

// ---------------------------------------------------------------------------
// Pack x[b][c][d] (f32) -> xb[c][b][d] (bf16)
// ---------------------------------------------------------------------------
__global__ __launch_bounds__(256) void cast_x(const float* __restrict__ x,
                                              unsigned short* __restrict__ xb) {
  const size_t i4 = ((size_t)blockIdx.x * 256 + threadIdx.x) * 4;
  const int    d  = (int)(i4 & (NN - 1));
  const size_t t  = i4 >> 11;
  const int    ch = (int)(t & (CCH - 1));
  const size_t b  = t >> 3;
  const float4 v  = *(const float4*)(x + i4);
  ushort4 o;
  o.x = f2bf(v.x); o.y = f2bf(v.y); o.z = f2bf(v.z); o.w = f2bf(v.w);
  *(ushort4*)&xb[((size_t)ch * NN + b) * NN + d] = o;
}

// ---------------------------------------------------------------------------
// W[c][d][o] (f32) -> Wt[c][o][d] (bf16), 32x32 LDS tile transpose.
// z in [0,16): z<8 -> Wq, else Wk; channel = z&7.
// ---------------------------------------------------------------------------
__global__ __launch_bounds__(256) void transpose_cast(const float* __restrict__ Wq,
                                                      const float* __restrict__ Wk,
                                                      unsigned short* __restrict__ Wqt,
                                                      unsigned short* __restrict__ Wkt) {
  const int z  = blockIdx.z;
  const int ch = z & 7;
  const float* src          = (z < 8 ? Wq : Wk) + (size_t)ch * NN * NN;
  unsigned short* dst       = (z < 8 ? Wqt : Wkt) + (size_t)ch * NN * NN;
  __shared__ float tile[32][33];
  const int o0 = blockIdx.x * 32;
  const int d0 = blockIdx.y * 32;
  const int tx = threadIdx.x, ty = threadIdx.y; // (32, 8)
#pragma unroll
  for (int k = 0; k < 4; ++k)
    tile[ty + 8 * k][tx] = src[(size_t)(d0 + ty + 8 * k) * NN + (o0 + tx)];
  __syncthreads();
#pragma unroll
  for (int k = 0; k < 4; ++k)
    dst[(size_t)(o0 + ty + 8 * k) * NN + (d0 + tx)] = f2bf(tile[tx][ty + 8 * k]);
}

// ---------------------------------------------------------------------------
// TN GEMM: C[m][n] = sum_k A[m][k] * B[n][k]  (A,B bf16 k-contiguous, fp32 acc)
// 128x128 tile, BK=32, 256 threads = 4 waves, each wave 64x64 via 4x4 MFMA 16x16x32.
// MODE 0 (QK):  epilogue v = acc + bias[m]; store bf16 C[m][n]; atomicAdd rowsum(v^2) -> accP[m]
// MODE 1 (EXP): v = exp(acc / max(sqrt(rowP[m]*colP[n]), 1e-12)); store bf16; rowsum(v) -> accP[m]
// MODE 2 (Z):   v = acc / colP[n]; store f32 to out[(m*CCH + c)*NN + n]
// ---------------------------------------------------------------------------
template <int MODE>
__global__ __launch_bounds__(256) void gemm_tn(const unsigned short* __restrict__ A,
                                               const unsigned short* __restrict__ B,
                                               void* __restrict__ Cout,
                                               const float* __restrict__ rowP,
                                               const float* __restrict__ colP,
                                               float* __restrict__ accP) {
  const int    c  = blockIdx.z;
  const size_t MS = (size_t)NN * NN;
  const unsigned short* Ac = A + (size_t)c * MS;
  const unsigned short* Bc = B + (size_t)c * MS;

  __shared__ __attribute__((aligned(16))) unsigned short As[128 * 32];
  __shared__ __attribute__((aligned(16))) unsigned short Bs[128 * 32];
  __shared__ float rsum[128];

  const int tid  = threadIdx.x;
  const int wave = tid >> 6;
  const int lane = tid & 63;
  const int wm   = wave >> 1;
  const int wn   = wave & 1;

  const int mBase = blockIdx.y * 128;
  const int nBase = blockIdx.x * 128;

  if (tid < 128) rsum[tid] = 0.0f;

  f32x4 acc[4][4] = {};

  // staging: wave w covers rows [w*32, w*32+32), 2 insts of 16 rows each.
  const int sRow = lane >> 2;
  const int sCol = (lane & 3) * 8;
  const unsigned short* Ag = Ac + (size_t)(mBase + wave * 32 + sRow) * NN + sCol;
  const unsigned short* Bg = Bc + (size_t)(nBase + wave * 32 + sRow) * NN + sCol;
  unsigned short* AsW = &As[(wave * 32) * 32];
  unsigned short* BsW = &Bs[(wave * 32) * 32];

  const int fr = lane & 15;        // fragment row/col within 16-tile
  const int fk = (lane >> 4) * 8;  // fragment k offset

  for (int k0 = 0; k0 < NN; k0 += 32) {
    async_load16(Ag + k0, AsW);
    async_load16(Ag + k0 + 16 * NN, AsW + 16 * 32);
    async_load16(Bg + k0, BsW);
    async_load16(Bg + k0 + 16 * NN, BsW + 16 * 32);
    __syncthreads();

    bf16x8 a[4], b[4];
#pragma unroll
    for (int i = 0; i < 4; ++i)
      a[i] = *(const bf16x8*)&As[(wm * 64 + i * 16 + fr) * 32 + fk];
#pragma unroll
    for (int j = 0; j < 4; ++j)
      b[j] = *(const bf16x8*)&Bs[(wn * 64 + j * 16 + fr) * 32 + fk];

#pragma unroll
    for (int i = 0; i < 4; ++i)
#pragma unroll
      for (int j = 0; j < 4; ++j)
        acc[i][j] = __builtin_amdgcn_mfma_f32_16x16x32_bf16(a[i], b[j], acc[i][j], 0, 0, 0);

    __syncthreads();
  }

  const int quad = lane >> 4;

  if constexpr (MODE == 0) {
    unsigned short* Co = (unsigned short*)Cout + (size_t)c * MS;
    const float* biasC = rowP + c * NN;
    float* dsq         = accP + c * NN;
#pragma unroll
    for (int i = 0; i < 4; ++i) {
#pragma unroll
      for (int r = 0; r < 4; ++r) {
        const int lrow  = wm * 64 + i * 16 + quad * 4 + r;
        const int row   = mBase + lrow;
        const float bias = biasC[row];
        float ss = 0.0f;
#pragma unroll
        for (int j = 0; j < 4; ++j) {
          const int col = nBase + wn * 64 + j * 16 + fr;
          float v = acc[i][j][r] + bias;
          Co[(size_t)row * NN + col] = f2bf(v);
          ss += v * v;
        }
#pragma unroll
        for (int m = 8; m >= 1; m >>= 1) ss += __shfl_xor(ss, m, 64);
        if (fr == 0) atomicAdd(&rsum[lrow], ss);
      }
    }
    __syncthreads();
    if (tid < 128) atomicAdd(&dsq[mBase + tid], rsum[tid]);
  } else if constexpr (MODE == 1) {
    unsigned short* Co = (unsigned short*)Cout + (size_t)c * MS;
    const float* dk2C  = rowP + c * NN;  // row index m = o
    const float* dq2C  = colP + c * NN;  // col index n = p
    float* csum        = accP + c * NN;
    float dq[4];
#pragma unroll
    for (int j = 0; j < 4; ++j) dq[j] = dq2C[nBase + wn * 64 + j * 16 + fr];
#pragma unroll
    for (int i = 0; i < 4; ++i) {
#pragma unroll
      for (int r = 0; r < 4; ++r) {
        const int lrow = wm * 64 + i * 16 + quad * 4 + r;
        const int row  = mBase + lrow;
        const float dk = dk2C[row];
        float es = 0.0f;
#pragma unroll
        for (int j = 0; j < 4; ++j) {
          const int col = nBase + wn * 64 + j * 16 + fr;
          const float denom = fmaxf(sqrtf(dk * dq[j]), 1e-12f);
          const float e = __expf(acc[i][j][r] / denom);  // |Y|<=1: no max-sub needed
          Co[(size_t)row * NN + col] = f2bf(e);
          es += e;
        }
#pragma unroll
        for (int m = 8; m >= 1; m >>= 1) es += __shfl_xor(es, m, 64);
        if (fr == 0) atomicAdd(&rsum[lrow], es);
      }
    }
    __syncthreads();
    if (tid < 128) atomicAdd(&csum[mBase + tid], rsum[tid]);
  } else {
    float* Co        = (float*)Cout;   // [B][C][D]
    const float* csC = colP + c * NN;  // colsum indexed by n = o
    float rcs[4];
#pragma unroll
    for (int j = 0; j < 4; ++j) rcs[j] = 1.0f / csC[nBase + wn * 64 + j * 16 + fr];
#pragma unroll
    for (int i = 0; i < 4; ++i) {
#pragma unroll
      for (int r = 0; r < 4; ++r) {
        const int row = mBase + wm * 64 + i * 16 + quad * 4 + r;  // b
#pragma unroll
        for (int j = 0; j < 4; ++j) {
          const int col = nBase + wn * 64 + j * 16 + fr;  // o
          Co[((size_t)row * CCH + c) * NN + col] = acc[i][j][r] * rcs[j];
        }
      }
    }
  }
}

// ---------------------------------------------------------------------------
extern "C" void kernel_launch(void* const* d_in, const int* in_sizes, int n_in,
                              void* d_out, int out_size, void* d_ws, size_t ws_size,
                              hipStream_t stream) {
  const float* x   = (const float*)d_in[0];
  const float* Wq  = (const float*)d_in[1];
  const float* Wq0 = (const float*)d_in[2];
  const float* Wk  = (const float*)d_in[3];
  const float* Wk0 = (const float*)d_in[4];

  const size_t S = (size_t)NN * NN * CCH;  // elements per big buffer (bf16 -> 2*S bytes)
  char* ws = (char*)d_ws;
  unsigned short* xb  = (unsigned short*)(ws);
  unsigned short* Wqt = (unsigned short*)(ws + 2 * S);
  unsigned short* Wkt = (unsigned short*)(ws + 4 * S);
  unsigned short* Qt  = (unsigned short*)(ws + 6 * S);
  unsigned short* Kt  = (unsigned short*)(ws + 8 * S);
  unsigned short* Et  = Wqt;  // Wqt dead after GEMM1q -> reuse for exp(Y)
  float* stats = (float*)(ws + 10 * S);
  float* dq2   = stats;                 // [C][D] sum_b Q^2
  float* dk2   = stats + CCH * NN;      // [C][D] sum_b K^2
  float* csum  = stats + 2 * CCH * NN;  // [C][D] softmax denominators

  hipMemsetAsync(stats, 0, 3 * CCH * NN * sizeof(float), stream);
  cast_x<<<32768, 256, 0, stream>>>(x, xb);
  transpose_cast<<<dim3(64, 64, 16), dim3(32, 8), 0, stream>>>(Wq, Wk, Wqt, Wkt);

  dim3 gg(16, 16, 8);
  // Qt[o][b] = sum_d Wqt[o][d]*xb[b][d] + q0[o];  dq2[o] += row sums of squares
  gemm_tn<0><<<gg, 256, 0, stream>>>(Wqt, xb, Qt, Wq0, nullptr, dq2);
  gemm_tn<0><<<gg, 256, 0, stream>>>(Wkt, xb, Kt, Wk0, nullptr, dk2);
  // Et[o][p] = exp( (sum_b Kt[o][b]*Qt[p][b]) / max(sqrt(dk2[o]*dq2[p]),eps) ); csum[o] += rowsum
  gemm_tn<1><<<gg, 256, 0, stream>>>(Kt, Qt, Et, dk2, dq2, csum);
  // Z[b][c][o] = (sum_p xb[b][p]*Et[o][p]) / csum[o]
  gemm_tn<2><<<gg, 256, 0, stream>>>(xb, Et, d_out, nullptr, csum, nullptr);
}